// Round 8
// baseline (194714.648 us; speedup 1.0000x reference)
//
#include <hip/hip_runtime.h>

// ---------------- problem constants ----------------
constexpr int kB  = 64;
constexpr int kS  = 512;
constexpr int kF  = 64;
constexpr int kH  = 512;
constexpr int kL  = 4;
constexpr int kDH = 64;
#define EPS 1e-5f

// ---------------- 1) recurrent scan: one WG (512 thr) per batch row ----------------
__global__ __launch_bounds__(512) void scan_kernel(
    const float* __restrict__ x,
    const float* __restrict__ Win0, const float* __restrict__ bin0,
    const float* __restrict__ Wi,   const float* __restrict__ bi,
    const float* __restrict__ Wh,   const float* __restrict__ bh,
    const float* __restrict__ Wo,   const float* __restrict__ bo,
    const float* __restrict__ lng,  const float* __restrict__ lnb,
    float* __restrict__ seq, float* __restrict__ seqmean)
{
  const int b = blockIdx.x;
  const int n = threadIdx.x;
  const int wid = n >> 6, lane = n & 63;

  __shared__ __align__(16) float sh_x[kF];
  __shared__ __align__(16) float sh_h[kH];
  __shared__ __align__(16) float sh_hs[kL][kH];
  __shared__ float red[16];

  #pragma unroll
  for (int l = 0; l < kL; ++l) sh_hs[l][n] = 0.f;
  float seqsum = 0.f;

  for (int t = 0; t < kS; ++t){
    __syncthreads();
    if (n < kF) sh_x[n] = x[((size_t)b*kS + t)*kF + n];
    __syncthreads();

    // h = x_t @ Win0^T + bin0
    float hn;
    {
      const float* w = Win0 + (size_t)n*kF;
      float a = bin0[n];
      for (int m = 0; m < kF; ++m) a += w[m] * sh_x[m];
      hn = a;
    }
    sh_h[n] = hn;
    __syncthreads();

    #pragma unroll 1
    for (int l = 0; l < kL; ++l){
      const size_t row = ((size_t)(l*kH + n)) * kH;
      // comb = h@Wi^T + bi + hs@Wh^T + bh
      float comb;
      {
        const float* wi = Wi + row;
        const float* wh = Wh + row;
        float a = bi[l*kH + n] + bh[l*kH + n];
        for (int m = 0; m < kH; ++m) a += wi[m]*sh_h[m] + wh[m]*sh_hs[l][m];
        comb = a;
      }
      float nh = sh_hs[l][n] + 0.1f * (comb - sh_hs[l][n]);
      __syncthreads();
      sh_hs[l][n] = nh;
      __syncthreads();
      // y = nh @ Wo^T + bo ; LayerNorm
      float y;
      {
        const float* wo = Wo + row;
        float a = bo[l*kH + n];
        for (int m = 0; m < kH; ++m) a += wo[m] * sh_hs[l][m];
        y = a;
      }
      float s1 = y, s2 = y*y;
      #pragma unroll
      for (int off = 32; off; off >>= 1){
        s1 += __shfl_down(s1, off); s2 += __shfl_down(s2, off);
      }
      if (lane == 0){ red[wid] = s1; red[8 + wid] = s2; }
      __syncthreads();
      float m = 0.f, q = 0.f;
      #pragma unroll
      for (int i = 0; i < 8; ++i){ m += red[i]; q += red[8 + i]; }
      m *= (1.f/kH); q *= (1.f/kH);
      const float var = q - m*m;
      hn = (y - m) * rsqrtf(var + EPS) * lng[l*kH + n] + lnb[l*kH + n];
      sh_h[n] = hn;
      __syncthreads();
    }
    seq[((size_t)b*kS + t)*kH + n] = hn;
    seqsum += hn;
  }
  seqmean[(size_t)b*kH + n] = seqsum * (1.f/kS);
}

// ---------------- 2) fused qkv-projection + flash attention (fp32) -------------
__global__ __launch_bounds__(512) void attn_kernel(
    const float* __restrict__ seq,    // (B,S,H)
    const float* __restrict__ ipw,    // (3H,H)
    const float* __restrict__ ipb,    // (3H)
    float* __restrict__ ao)           // (B,S,H): per-head attn@v (pre out-proj)
{
  constexpr int TP = 128, RPF = 68;
  const int bh = blockIdx.x;
  const int b = bh >> 3, h = bh & 7;
  const int tid = threadIdx.x;

  __shared__ float kt[TP][RPF];
  __shared__ float vt[TP][RPF];

  // q = (seq_row @ Wq^T + bq) / 8
  const float* srow_q = seq + ((size_t)(b*kS) + tid)*kH;
  float qr[kDH];
  #pragma unroll 1
  for (int d = 0; d < kDH; ++d){
    const float* w = ipw + (size_t)(h*kDH + d)*kH;
    float a = ipb[h*kDH + d];
    for (int m = 0; m < kH; ++m) a += w[m] * srow_q[m];
    qr[d] = a * 0.125f;
  }

  float o[kDH];
  #pragma unroll
  for (int d = 0; d < kDH; ++d) o[d] = 0.f;
  float mmax = -1e30f, lsum = 0.f;

  const int p  = tid & (TP - 1);
  const int dg = (tid >> 7) * 16;

  for (int t0 = 0; t0 < kS; t0 += TP){
    __syncthreads();
    const float* srow = seq + ((size_t)(b*kS) + t0 + p)*kH;
    #pragma unroll 1
    for (int dd = 0; dd < 16; ++dd){
      const int d = dg + dd;
      const float* wk = ipw + (size_t)(kH   + h*kDH + d)*kH;
      const float* wv = ipw + (size_t)(2*kH + h*kDH + d)*kH;
      float ak = ipb[kH + h*kDH + d], av = ipb[2*kH + h*kDH + d];
      for (int m = 0; m < kH; ++m){ ak += wk[m]*srow[m]; av += wv[m]*srow[m]; }
      kt[p][d] = ak; vt[p][d] = av;
    }
    __syncthreads();

    for (int j = 0; j < TP; ++j){
      float s = 0.f;
      #pragma unroll
      for (int d = 0; d < kDH; ++d) s += qr[d] * kt[j][d];
      if (s > mmax){                  // exact online softmax
        const float corr = __expf(mmax - s);
        lsum *= corr;
        #pragma unroll
        for (int d = 0; d < kDH; ++d) o[d] *= corr;
        mmax = s;
      }
      const float pw = __expf(s - mmax);
      lsum += pw;
      #pragma unroll
      for (int d = 0; d < kDH; ++d) o[d] += pw * vt[j][d];
    }
  }

  const float invl = 1.f / lsum;
  float* aorow = ao + ((size_t)(b*kS) + tid)*kH + h*kDH;
  #pragma unroll
  for (int d = 0; d < kDH; ++d) aorow[d] = o[d] * invl;
}

// ---------------- 3) mean over S of ao ----------------
__global__ __launch_bounds__(512) void aosum_kernel(const float* __restrict__ ao,
                                                    float* __restrict__ aomean)
{
  const int b = blockIdx.x, n = threadIdx.x;
  float acc = 0.f;
  for (int s = 0; s < kS; ++s) acc += ao[((size_t)(b*kS) + s)*kH + n];
  aomean[(size_t)b*kH + n] = acc * (1.f/kS);
}

// ---- 4) pooled = mean_s(seq) + mean_s(ao)@out_w^T + out_b (mean is linear) ----
__global__ __launch_bounds__(512) void pooled_kernel(
    const float* __restrict__ seqmean, const float* __restrict__ aomean,
    const float* __restrict__ outw, const float* __restrict__ outb,
    float* __restrict__ pooled)
{
  const int b = blockIdx.x, n = threadIdx.x;
  __shared__ float a[kH];
  a[n] = aomean[(size_t)b*kH + n];
  __syncthreads();
  const float* w = outw + (size_t)n*kH;
  float acc = outb[n];
  for (int m = 0; m < kH; ++m) acc += w[m] * a[m];
  pooled[(size_t)b*kH + n] = seqmean[(size_t)b*kH + n] + acc;
}

// ---------------- 5) heads — OUTPUT IS FP32 (the R8 fix) ----------------
__global__ __launch_bounds__(256) void heads_kernel(
    const float* __restrict__ pooled,
    const float* Wd1, const float* bd1, const float* Wd2, const float* bd2,
    const float* Wd3, const float* bd3,
    const float* Wq1, const float* bq1, const float* Wq2, const float* bq2,
    const float* Wq3, const float* bq3,
    const float* Wc1, const float* bc1, const float* Wc2, const float* bc2,
    float* __restrict__ out)
{
  const int b = blockIdx.x, tid = threadIdx.x;
  __shared__ float p[kH];
  __shared__ float a1d[256], a1q[256], a1c[256];
  __shared__ float a2d[128], a2q[128];
  p[tid]       = pooled[(size_t)b*kH + tid];
  p[tid + 256] = pooled[(size_t)b*kH + tid + 256];
  __syncthreads();
  {
    const float *w1 = Wd1 + (size_t)tid*kH, *w2 = Wq1 + (size_t)tid*kH,
                *w3 = Wc1 + (size_t)tid*kH;
    float v1 = bd1[tid], v2 = bq1[tid], v3 = bc1[tid];
    for (int m = 0; m < kH; ++m){
      v1 += w1[m]*p[m]; v2 += w2[m]*p[m]; v3 += w3[m]*p[m];
    }
    a1d[tid] = fmaxf(v1, 0.f); a1q[tid] = fmaxf(v2, 0.f); a1c[tid] = fmaxf(v3, 0.f);
  }
  __syncthreads();
  if (tid < 128){
    const float *w1 = Wd2 + (size_t)tid*256, *w2 = Wq2 + (size_t)tid*256;
    float v1 = bd2[tid], v2 = bq2[tid];
    for (int m = 0; m < 256; ++m){ v1 += w1[m]*a1d[m]; v2 += w2[m]*a1q[m]; }
    a2d[tid] = fmaxf(v1, 0.f); a2q[tid] = fmaxf(v2, 0.f);
  }
  __syncthreads();
  if (tid == 0){
    float d0 = bd3[0], d1 = bd3[1], pr = bq3[0], c = bc2[0];
    for (int m = 0; m < 128; ++m){
      d0 += Wd3[m]*a2d[m]; d1 += Wd3[128+m]*a2d[m]; pr += Wq3[m]*a2q[m];
    }
    for (int m = 0; m < 256; ++m) c += Wc2[m]*a1c[m];
    c = 1.f / (1.f + __expf(-c));
    out[2*b + 0]  = d0;             // direction_logits (64,2), flat [0:128)
    out[2*b + 1]  = d1;
    out[2*kB + b] = pr;             // price_target (64,1), flat [128:192)
    out[3*kB + b] = c;              // confidence (64,1), flat [192:256)
  }
}

// ---------------- launch ----------------
extern "C" void kernel_launch(void* const* d_in, const int* in_sizes, int n_in,
                              void* d_out, int out_size, void* d_ws, size_t ws_size,
                              hipStream_t stream) {
  const float* x    = (const float*)d_in[0];
  const float* Win0 = (const float*)d_in[1];
  const float* bin0 = (const float*)d_in[2];
  const float* Wi   = (const float*)d_in[3];
  const float* bi   = (const float*)d_in[4];
  const float* Wh   = (const float*)d_in[5];
  const float* bh   = (const float*)d_in[6];
  const float* Wo   = (const float*)d_in[7];
  const float* bo   = (const float*)d_in[8];
  const float* lng  = (const float*)d_in[9];
  const float* lnb  = (const float*)d_in[10];
  const float* ipw  = (const float*)d_in[11];
  const float* ipb  = (const float*)d_in[12];
  const float* outw = (const float*)d_in[13];
  const float* outb = (const float*)d_in[14];
  const float* Wd1  = (const float*)d_in[15];
  const float* bd1  = (const float*)d_in[16];
  const float* Wd2  = (const float*)d_in[17];
  const float* bd2  = (const float*)d_in[18];
  const float* Wd3  = (const float*)d_in[19];
  const float* bd3  = (const float*)d_in[20];
  const float* Wq1  = (const float*)d_in[21];
  const float* bq1  = (const float*)d_in[22];
  const float* Wq2  = (const float*)d_in[23];
  const float* bq2  = (const float*)d_in[24];
  const float* Wq3  = (const float*)d_in[25];
  const float* bq3  = (const float*)d_in[26];
  const float* Wc1  = (const float*)d_in[27];
  const float* bc1  = (const float*)d_in[28];
  const float* Wc2  = (const float*)d_in[29];
  const float* bc2  = (const float*)d_in[30];

  constexpr size_t SEQ_F = (size_t)kB*kS*kH;
  float* seq     = (float*)d_ws;
  float* ao      = seq + SEQ_F;
  float* seqmean = ao + SEQ_F;
  float* aomean  = seqmean + (size_t)kB*kH;
  float* pooled  = aomean  + (size_t)kB*kH;

  scan_kernel<<<kB, kH, 0, stream>>>(x, Win0, bin0, Wi, bi, Wh, bh, Wo, bo,
                                     lng, lnb, seq, seqmean);

  attn_kernel<<<kB*8, 512, 0, stream>>>(seq, ipw, ipb, ao);

  aosum_kernel<<<kB, kH, 0, stream>>>(ao, aomean);

  pooled_kernel<<<kB, kH, 0, stream>>>(seqmean, aomean, outw, outb, pooled);

  heads_kernel<<<kB, 256, 0, stream>>>(pooled,
      Wd1, bd1, Wd2, bd2, Wd3, bd3,
      Wq1, bq1, Wq2, bq2, Wq3, bq3,
      Wc1, bc1, Wc2, bc2, (float*)d_out);
}

// Round 9
// 19246.095 us; speedup vs baseline: 10.1171x; 10.1171x over previous
//
#include <hip/hip_runtime.h>

// ---------------- problem constants ----------------
constexpr int kB  = 64;
constexpr int kS  = 512;
constexpr int kF  = 64;
constexpr int kH  = 512;
constexpr int kL  = 4;
constexpr int kDH = 64;
#define EPS 1e-5f

typedef __attribute__((ext_vector_type(8))) short short8;
typedef __attribute__((ext_vector_type(4))) float f32x4;

// ---------------- bf16 helpers ----------------
__device__ __forceinline__ ushort f2b(float f){
  unsigned u; __builtin_memcpy(&u, &f, 4);
  unsigned r = (u + 0x7fffu + ((u >> 16) & 1u)) >> 16;  // RNE
  return (ushort)r;
}
__device__ __forceinline__ float b2f(ushort u){
  unsigned v = ((unsigned)u) << 16; float f; __builtin_memcpy(&f, &v, 4); return f;
}
__device__ __forceinline__ void unpack2(unsigned u, float& a, float& b){
  unsigned lo = u << 16, hi = u & 0xffff0000u;
  __builtin_memcpy(&a, &lo, 4); __builtin_memcpy(&b, &hi, 4);
}

// ---------------- prep: fp32 -> bf16 cast with scale ----------------
__global__ void cast_scale(const float* __restrict__ src, ushort* __restrict__ dst,
                           int n, float s){
  int i = blockIdx.x*256 + threadIdx.x;
  if (i < n) dst[i] = f2b(src[i]*s);
}

// G4[l][(m>>2)*2048 + n*4 + (m&3)] = bf16(0.1*Wh[l][n][m])  (pack-4 along m)
__global__ void prep_g4(const float* __restrict__ Wh, ushort* __restrict__ G4){
  int i = blockIdx.x*256 + threadIdx.x;
  if (i >= kL*kH*kH) return;
  const int l = i >> 18, rem = i & 262143;
  const int m = rem >> 9, n = rem & 511;
  const float v = 0.1f * Wh[(size_t)l*kH*kH + (size_t)n*kH + m];
  G4[(size_t)l*kH*kH + (size_t)(m>>2)*2048 + n*4 + (m&3)] = f2b(v);
}

// ---------------- MFMA GEMM: C[M,N](bf16) = A[M,K](bf16) @ W[N,K]^T + bias ----
// wave tile 16(m) x 64(n), 4 waves/block. bias = bscale*(pb1[n]+pb2[n])
__global__ __launch_bounds__(256) void gemm_bf16(
    const ushort* __restrict__ A, const ushort* __restrict__ W,
    ushort* __restrict__ C, int M, int N, int K,
    const float* __restrict__ pb1, const float* __restrict__ pb2, float bscale)
{
  const int wave = threadIdx.x >> 6, lane = threadIdx.x & 63;
  const int task = blockIdx.x*4 + wave;
  const int NT = N >> 6;
  const int mt = task / NT, ng = task % NT;
  const int r = lane & 15, quad = lane >> 4;

  const ushort* ap = A + (size_t)(mt*16 + r)*K + quad*8;
  const ushort* wp = W + (size_t)(ng*64 + r)*K + quad*8;
  f32x4 ac0 = {0,0,0,0}, ac1 = {0,0,0,0}, ac2 = {0,0,0,0}, ac3 = {0,0,0,0};
  for (int k0 = 0; k0 < K; k0 += 32){
    short8 av = *(const short8*)(ap + k0);
    short8 b0 = *(const short8*)(wp + k0);
    short8 b1 = *(const short8*)(wp + (size_t)16*K + k0);
    short8 b2 = *(const short8*)(wp + (size_t)32*K + k0);
    short8 b3 = *(const short8*)(wp + (size_t)48*K + k0);
    ac0 = __builtin_amdgcn_mfma_f32_16x16x32_bf16(av, b0, ac0, 0, 0, 0);
    ac1 = __builtin_amdgcn_mfma_f32_16x16x32_bf16(av, b1, ac1, 0, 0, 0);
    ac2 = __builtin_amdgcn_mfma_f32_16x16x32_bf16(av, b2, ac2, 0, 0, 0);
    ac3 = __builtin_amdgcn_mfma_f32_16x16x32_bf16(av, b3, ac3, 0, 0, 0);
  }
  const f32x4 accs[4] = {ac0, ac1, ac2, ac3};
  #pragma unroll
  for (int j = 0; j < 4; ++j){
    const int nn = ng*64 + j*16 + r;
    float bias = 0.f;
    if (pb1) bias += pb1[nn];
    if (pb2) bias += pb2[nn];
    bias *= bscale;
    #pragma unroll
    for (int i = 0; i < 4; ++i){
      const int mm = mt*16 + quad*4 + i;
      C[(size_t)mm*N + nn] = f2b(accs[j][i] + bias);
    }
  }
}

// ---------------- sequential scan: hs_t = 0.9*hs + U_t + hs@G ----------------
// one WG per batch row; G bf16 pack-4 coalesced; hs fp32 in LDS.
__global__ __launch_bounds__(512) void scan_step(
    const ushort* __restrict__ U, const ushort* __restrict__ G4,
    ushort* __restrict__ nh)
{
  const int b = blockIdx.x, n = threadIdx.x;
  __shared__ __align__(16) float hs[kH];
  hs[n] = 0.f;
  __syncthreads();
  const ushort* g = G4 + n*4;
  for (int t = 0; t < kS; ++t){
    const float u = b2f(U[((size_t)b*kS + t)*kH + n]);
    float acc = 0.f;
    #pragma unroll 8
    for (int m4 = 0; m4 < kH/4; ++m4){
      const uint2 p = *(const uint2*)(g + m4*2048);
      const float4 hh = *(const float4*)&hs[m4*4];   // broadcast b128
      float g0,g1,g2,g3;
      unpack2(p.x, g0, g1); unpack2(p.y, g2, g3);
      acc += hh.x*g0 + hh.y*g1 + hh.z*g2 + hh.w*g3;
    }
    const float nv = 0.9f*hs[n] + u + acc;
    __syncthreads();
    hs[n] = nv;
    nh[((size_t)b*kS + t)*kH + n] = f2b(nv);
    __syncthreads();
  }
}

// ---------------- LayerNorm rows (in place on bf16) ----------------
__global__ __launch_bounds__(512) void ln_rows(
    ushort* __restrict__ act, const float* __restrict__ g, const float* __restrict__ bta)
{
  const size_t row = blockIdx.x;
  const int n = threadIdx.x, wid = n >> 6, lane = n & 63;
  __shared__ float red[16];
  const float y = b2f(act[row*kH + n]);
  float s1 = y, s2 = y*y;
  #pragma unroll
  for (int off = 32; off; off >>= 1){
    s1 += __shfl_down(s1, off); s2 += __shfl_down(s2, off);
  }
  if (lane == 0){ red[wid] = s1; red[8 + wid] = s2; }
  __syncthreads();
  float m = 0.f, q = 0.f;
  #pragma unroll
  for (int i = 0; i < 8; ++i){ m += red[i]; q += red[8+i]; }
  m *= (1.f/kH); q *= (1.f/kH);
  const float var = q - m*m;
  const float hv = (y - m) * rsqrtf(var + EPS) * g[n] + bta[n];
  act[row*kH + n] = f2b(hv);
}

// ---------------- seqmean (fp32) from bf16 act ----------------
__global__ __launch_bounds__(512) void seqmean_k(
    const ushort* __restrict__ act, float* __restrict__ seqmean)
{
  const int b = blockIdx.x, n = threadIdx.x;
  float acc = 0.f;
  for (int t = 0; t < kS; ++t) acc += b2f(act[((size_t)b*kS + t)*kH + n]);
  seqmean[(size_t)b*kH + n] = acc * (1.f/kS);
}

// ---------------- flash attention on precomputed qkv (bf16) ----------------
// block = (bb, h) within a 16-batch chunk; 512 threads = 512 queries.
__global__ __launch_bounds__(512) void attn_chunk(
    const ushort* __restrict__ qkv,   // (16*S, 3H) bf16
    float* __restrict__ aomean, int b0)
{
  const int bb = blockIdx.x >> 3, h = blockIdx.x & 7;
  const int tid = threadIdx.x, lane = tid & 63;
  __shared__ ushort kt[128][72];
  __shared__ ushort vt[128][72];
  __shared__ float aom[kDH];
  if (tid < kDH) aom[tid] = 0.f;

  float q[kDH], o[kDH];
  {
    const uint4* qp = (const uint4*)(qkv + ((size_t)bb*kS + tid)*(3*kH) + h*kDH);
    #pragma unroll
    for (int i = 0; i < 8; ++i){
      uint4 u = qp[i]; float f0,f1,f2,f3,f4,f5,f6,f7;
      unpack2(u.x,f0,f1); unpack2(u.y,f2,f3); unpack2(u.z,f4,f5); unpack2(u.w,f6,f7);
      q[i*8+0]=f0*0.125f; q[i*8+1]=f1*0.125f; q[i*8+2]=f2*0.125f; q[i*8+3]=f3*0.125f;
      q[i*8+4]=f4*0.125f; q[i*8+5]=f5*0.125f; q[i*8+6]=f6*0.125f; q[i*8+7]=f7*0.125f;
    }
  }
  #pragma unroll
  for (int d = 0; d < kDH; ++d) o[d] = 0.f;
  float mmax = -1e30f, lsum = 0.f;

  const int p  = tid & 127;
  const int dg = (tid >> 7) * 16;

  for (int t0 = 0; t0 < kS; t0 += 128){
    __syncthreads();
    const ushort* krow = qkv + ((size_t)bb*kS + t0 + p)*(3*kH) + kH   + h*kDH + dg;
    const ushort* vrow = qkv + ((size_t)bb*kS + t0 + p)*(3*kH) + 2*kH + h*kDH + dg;
    *(uint4*)&kt[p][dg]     = *(const uint4*)krow;
    *(uint4*)&kt[p][dg + 8] = *(const uint4*)(krow + 8);
    *(uint4*)&vt[p][dg]     = *(const uint4*)vrow;
    *(uint4*)&vt[p][dg + 8] = *(const uint4*)(vrow + 8);
    __syncthreads();

    for (int j = 0; j < 128; ++j){
      float s = 0.f;
      const uint4* kp = (const uint4*)&kt[j][0];
      #pragma unroll
      for (int i = 0; i < 8; ++i){
        uint4 u = kp[i]; float f0,f1,f2,f3,f4,f5,f6,f7;
        unpack2(u.x,f0,f1); unpack2(u.y,f2,f3); unpack2(u.z,f4,f5); unpack2(u.w,f6,f7);
        s += q[i*8+0]*f0 + q[i*8+1]*f1 + q[i*8+2]*f2 + q[i*8+3]*f3
           + q[i*8+4]*f4 + q[i*8+5]*f5 + q[i*8+6]*f6 + q[i*8+7]*f7;
      }
      if (s > mmax){
        const float corr = __expf(mmax - s);
        lsum *= corr;
        #pragma unroll
        for (int d = 0; d < kDH; ++d) o[d] *= corr;
        mmax = s;
      }
      const float pw = __expf(s - mmax);
      lsum += pw;
      const uint4* vp = (const uint4*)&vt[j][0];
      #pragma unroll
      for (int i = 0; i < 8; ++i){
        uint4 u = vp[i]; float f0,f1,f2,f3,f4,f5,f6,f7;
        unpack2(u.x,f0,f1); unpack2(u.y,f2,f3); unpack2(u.z,f4,f5); unpack2(u.w,f6,f7);
        o[i*8+0] += pw*f0; o[i*8+1] += pw*f1; o[i*8+2] += pw*f2; o[i*8+3] += pw*f3;
        o[i*8+4] += pw*f4; o[i*8+5] += pw*f5; o[i*8+6] += pw*f6; o[i*8+7] += pw*f7;
      }
    }
  }
  const float invl = 1.f / lsum;
  #pragma unroll
  for (int d = 0; d < kDH; ++d){
    float v = o[d] * invl;
    #pragma unroll
    for (int off = 32; off; off >>= 1) v += __shfl_down(v, off);
    if (lane == 0) atomicAdd(&aom[d], v);
  }
  __syncthreads();
  if (tid < kDH)
    aomean[(size_t)(b0 + bb)*kH + h*kDH + tid] = aom[tid] * (1.f/kS);
}

// ---- pooled = seqmean + aomean@out_w^T + out_b (fp32, validated in R8) ----
__global__ __launch_bounds__(512) void pooled_kernel(
    const float* __restrict__ seqmean, const float* __restrict__ aomean,
    const float* __restrict__ outw, const float* __restrict__ outb,
    float* __restrict__ pooled)
{
  const int b = blockIdx.x, n = threadIdx.x;
  __shared__ float a[kH];
  a[n] = aomean[(size_t)b*kH + n];
  __syncthreads();
  const float* w = outw + (size_t)n*kH;
  float acc = outb[n];
  for (int m = 0; m < kH; ++m) acc += w[m] * a[m];
  pooled[(size_t)b*kH + n] = seqmean[(size_t)b*kH + n] + acc;
}

// ---------------- heads (fp32, validated in R8) ----------------
__global__ __launch_bounds__(256) void heads_kernel(
    const float* __restrict__ pooled,
    const float* Wd1, const float* bd1, const float* Wd2, const float* bd2,
    const float* Wd3, const float* bd3,
    const float* Wq1, const float* bq1, const float* Wq2, const float* bq2,
    const float* Wq3, const float* bq3,
    const float* Wc1, const float* bc1, const float* Wc2, const float* bc2,
    float* __restrict__ out)
{
  const int b = blockIdx.x, tid = threadIdx.x;
  __shared__ float p[kH];
  __shared__ float a1d[256], a1q[256], a1c[256];
  __shared__ float a2d[128], a2q[128];
  p[tid]       = pooled[(size_t)b*kH + tid];
  p[tid + 256] = pooled[(size_t)b*kH + tid + 256];
  __syncthreads();
  {
    const float *w1 = Wd1 + (size_t)tid*kH, *w2 = Wq1 + (size_t)tid*kH,
                *w3 = Wc1 + (size_t)tid*kH;
    float v1 = bd1[tid], v2 = bq1[tid], v3 = bc1[tid];
    for (int m = 0; m < kH; ++m){
      v1 += w1[m]*p[m]; v2 += w2[m]*p[m]; v3 += w3[m]*p[m];
    }
    a1d[tid] = fmaxf(v1, 0.f); a1q[tid] = fmaxf(v2, 0.f); a1c[tid] = fmaxf(v3, 0.f);
  }
  __syncthreads();
  if (tid < 128){
    const float *w1 = Wd2 + (size_t)tid*256, *w2 = Wq2 + (size_t)tid*256;
    float v1 = bd2[tid], v2 = bq2[tid];
    for (int m = 0; m < 256; ++m){ v1 += w1[m]*a1d[m]; v2 += w2[m]*a1q[m]; }
    a2d[tid] = fmaxf(v1, 0.f); a2q[tid] = fmaxf(v2, 0.f);
  }
  __syncthreads();
  if (tid == 0){
    float d0 = bd3[0], d1 = bd3[1], pr = bq3[0], c = bc2[0];
    for (int m = 0; m < 128; ++m){
      d0 += Wd3[m]*a2d[m]; d1 += Wd3[128+m]*a2d[m]; pr += Wq3[m]*a2q[m];
    }
    for (int m = 0; m < 256; ++m) c += Wc2[m]*a1c[m];
    c = 1.f / (1.f + __expf(-c));
    out[2*b + 0]  = d0;
    out[2*b + 1]  = d1;
    out[2*kB + b] = pr;
    out[3*kB + b] = c;
  }
}

// ---------------- launch ----------------
extern "C" void kernel_launch(void* const* d_in, const int* in_sizes, int n_in,
                              void* d_out, int out_size, void* d_ws, size_t ws_size,
                              hipStream_t stream) {
  const float* x    = (const float*)d_in[0];
  const float* Win0 = (const float*)d_in[1];
  const float* bin0 = (const float*)d_in[2];
  const float* Wi   = (const float*)d_in[3];
  const float* bi   = (const float*)d_in[4];
  const float* Wh   = (const float*)d_in[5];
  const float* bh   = (const float*)d_in[6];
  const float* Wo   = (const float*)d_in[7];
  const float* bo   = (const float*)d_in[8];
  const float* lng  = (const float*)d_in[9];
  const float* lnb  = (const float*)d_in[10];
  const float* ipw  = (const float*)d_in[11];
  const float* ipb  = (const float*)d_in[12];
  const float* outw = (const float*)d_in[13];
  const float* outb = (const float*)d_in[14];

  char* wsb = (char*)d_ws;
  // regions (bytes)
  ushort* act   = (ushort*)(wsb);                              // 32 MiB bf16
  ushort* U     = (ushort*)(wsb + (32u<<20));                  // 32 MiB bf16 (reused as qkv)
  ushort* nh    = (ushort*)(wsb + (64u<<20));                  // 32 MiB bf16
  ushort* G4    = (ushort*)(wsb + (96u<<20));                  // 2 MiB
  ushort* wi_bf = (ushort*)(wsb + (96u<<20) + (2u<<20));       // 2 MiB (0.1-scaled)
  ushort* wo_bf = (ushort*)(wsb + (96u<<20) + (4u<<20));       // 2 MiB
  ushort* w0_bf = (ushort*)(wsb + (96u<<20) + (6u<<20));       // 64 KiB
  ushort* ip_bf = (ushort*)(wsb + (96u<<20) + (6u<<20) + 65536);          // 1.5 MiB
  ushort* x_bf  = (ushort*)(wsb + (96u<<20) + (6u<<20) + 65536 + 1572864);// 4 MiB
  char*   tail  = wsb + (96u<<20) + (6u<<20) + 65536 + 1572864 + 4194304;
  float* seqmean = (float*)tail;
  float* aomean  = seqmean + (size_t)kB*kH;
  float* pooled  = aomean  + (size_t)kB*kH;
  ushort* qkv    = U;   // overlay: U dead after the scan phase

  // ---- prep casts ----
  cast_scale<<<(kB*kS*kF + 255)/256, 256, 0, stream>>>(x, x_bf, kB*kS*kF, 1.f);
  cast_scale<<<(kH*kF + 255)/256, 256, 0, stream>>>(Win0, w0_bf, kH*kF, 1.f);
  cast_scale<<<(kL*kH*kH + 255)/256, 256, 0, stream>>>(Wi, wi_bf, kL*kH*kH, 0.1f);
  cast_scale<<<(kL*kH*kH + 255)/256, 256, 0, stream>>>(Wo, wo_bf, kL*kH*kH, 1.f);
  cast_scale<<<(3*kH*kH + 255)/256, 256, 0, stream>>>(ipw, ip_bf, 3*kH*kH, 1.f);
  prep_g4<<<(kL*kH*kH + 255)/256, 256, 0, stream>>>(Wh, G4);

  constexpr int M = kB*kS;   // 32768
  // ---- input projection: act = x @ Win0^T + bin0 ----
  gemm_bf16<<<(M/16)*(kH/64)/4, 256, 0, stream>>>(x_bf, w0_bf, act, M, kH, kF,
                                                  bin0, nullptr, 1.f);
  // ---- per layer: hoisted GEMMs + minimal sequential scan ----
  for (int l = 0; l < kL; ++l){
    gemm_bf16<<<(M/16)*(kH/64)/4, 256, 0, stream>>>(
        act, wi_bf + (size_t)l*kH*kH, U, M, kH, kH,
        bi + (size_t)l*kH, bh + (size_t)l*kH, 0.1f);
    scan_step<<<kB, kH, 0, stream>>>(U, G4 + (size_t)l*kH*kH, nh);
    gemm_bf16<<<(M/16)*(kH/64)/4, 256, 0, stream>>>(
        nh, wo_bf + (size_t)l*kH*kH, act, M, kH, kH,
        bo + (size_t)l*kH, nullptr, 1.f);
    ln_rows<<<M, kH, 0, stream>>>(act, lng + (size_t)l*kH, lnb + (size_t)l*kH);
  }

  seqmean_k<<<kB, kH, 0, stream>>>(act, seqmean);

  // ---- attention in 4 batch chunks of 16 (qkv overlays U) ----
  for (int c = 0; c < 4; ++c){
    const int Mc = 16*kS;   // 8192
    gemm_bf16<<<(Mc/16)*(3*kH/64)/4, 256, 0, stream>>>(
        act + (size_t)c*Mc*kH, ip_bf, qkv, Mc, 3*kH, kH, ipb, nullptr, 1.f);
    attn_chunk<<<16*8, kH, 0, stream>>>(qkv, aomean, c*16);
  }

  pooled_kernel<<<kB, kH, 0, stream>>>(seqmean, aomean, outw, outb, pooled);

  heads_kernel<<<kB, 256, 0, stream>>>(pooled,
      (const float*)d_in[15], (const float*)d_in[16], (const float*)d_in[17],
      (const float*)d_in[18], (const float*)d_in[19], (const float*)d_in[20],
      (const float*)d_in[21], (const float*)d_in[22], (const float*)d_in[23],
      (const float*)d_in[24], (const float*)d_in[25], (const float*)d_in[26],
      (const float*)d_in[27], (const float*)d_in[28], (const float*)d_in[29],
      (const float*)d_in[30], (float*)d_out);
}

// Round 10
// 9015.799 us; speedup vs baseline: 21.5970x; 2.1347x over previous
//
#include <hip/hip_runtime.h>

// ---------------- problem constants ----------------
constexpr int kB  = 64;
constexpr int kS  = 512;
constexpr int kF  = 64;
constexpr int kH  = 512;
constexpr int kL  = 4;
constexpr int kDH = 64;
constexpr int kC  = 32;              // chunk length
constexpr int kNC = kS / kC;         // 16 chunks
#define EPS 1e-5f

typedef __attribute__((ext_vector_type(8))) short short8;
typedef __attribute__((ext_vector_type(4))) float f32x4;

// ---------------- bf16 helpers ----------------
__device__ __forceinline__ ushort f2b(float f){
  unsigned u; __builtin_memcpy(&u, &f, 4);
  unsigned r = (u + 0x7fffu + ((u >> 16) & 1u)) >> 16;  // RNE
  return (ushort)r;
}
__device__ __forceinline__ float b2f(ushort u){
  unsigned v = ((unsigned)u) << 16; float f; __builtin_memcpy(&f, &v, 4); return f;
}
__device__ __forceinline__ void unpack2(unsigned u, float& a, float& b){
  unsigned lo = u << 16, hi = u & 0xffff0000u;
  __builtin_memcpy(&a, &lo, 4); __builtin_memcpy(&b, &hi, 4);
}

// ---------------- prep: fp32 -> bf16 cast with scale ----------------
__global__ void cast_scale(const float* __restrict__ src, ushort* __restrict__ dst,
                           int n, float s){
  int i = blockIdx.x*256 + threadIdx.x;
  if (i < n) dst[i] = f2b(src[i]*s);
}

// G8[l][(m>>3)*4096 + n*8 + (m&7)] = bf16(0.1*Wh[l][n][m])  (pack-8 along m)
__global__ void prep_g8(const float* __restrict__ Wh, ushort* __restrict__ G8){
  int i = blockIdx.x*256 + threadIdx.x;
  if (i >= kL*kH*kH) return;
  const int l = i >> 18, rem = i & 262143;
  const int m = rem >> 9, n = rem & 511;
  const float v = 0.1f * Wh[(size_t)l*kH*kH + (size_t)n*kH + m];
  G8[(size_t)l*kH*kH + (size_t)(m>>3)*4096 + n*8 + (m&7)] = f2b(v);
}

// Afp[l][m][n] = (m==n ? 0.9 : 0) + float(bf16(0.1*Wh[l][n][m]))  -- row-major fp32
__global__ void prep_afp(const float* __restrict__ Wh, float* __restrict__ Afp){
  int i = blockIdx.x*256 + threadIdx.x;
  if (i >= kL*kH*kH) return;
  const int l = i >> 18, rem = i & 262143;
  const int m = rem >> 9, n = rem & 511;
  float v = b2f(f2b(0.1f * Wh[(size_t)l*kH*kH + (size_t)n*kH + m]));
  if (m == n) v += 0.9f;
  Afp[(size_t)l*kH*kH + (size_t)m*kH + n] = v;
}

// fp32 squaring GEMM, batched over 4 layers: Out[l] = In[l] @ In[l]
__global__ __launch_bounds__(512) void sqgemm(const float* __restrict__ In,
                                              float* __restrict__ Out){
  const int l = blockIdx.x >> 6;       // 4 layers
  const int rg = blockIdx.x & 63;      // row-group of 8
  const int j = threadIdx.x;
  const float* A = In + (size_t)l*kH*kH;
  float* C = Out + (size_t)l*kH*kH;
  __shared__ float ar[8][kH];
  #pragma unroll
  for (int r = 0; r < 8; ++r) ar[r][j] = A[(size_t)(rg*8 + r)*kH + j];
  __syncthreads();
  float acc[8] = {0,0,0,0,0,0,0,0};
  for (int k = 0; k < kH; ++k){
    const float bkj = A[(size_t)k*kH + j];
    #pragma unroll
    for (int r = 0; r < 8; ++r) acc[r] += ar[r][k] * bkj;
  }
  #pragma unroll
  for (int r = 0; r < 8; ++r) C[(size_t)(rg*8 + r)*kH + j] = acc[r];
}

// ---------------- MFMA GEMM: C[M,N](bf16) = A[M,K](bf16) @ W[N,K]^T + bias ----
__global__ __launch_bounds__(256) void gemm_bf16(
    const ushort* __restrict__ A, const ushort* __restrict__ W,
    ushort* __restrict__ C, int M, int N, int K,
    const float* __restrict__ pb1, const float* __restrict__ pb2, float bscale)
{
  const int wave = threadIdx.x >> 6, lane = threadIdx.x & 63;
  const int task = blockIdx.x*4 + wave;
  const int NT = N >> 6;
  const int mt = task / NT, ng = task % NT;
  const int r = lane & 15, quad = lane >> 4;

  const ushort* ap = A + (size_t)(mt*16 + r)*K + quad*8;
  const ushort* wp = W + (size_t)(ng*64 + r)*K + quad*8;
  f32x4 ac0 = {0,0,0,0}, ac1 = {0,0,0,0}, ac2 = {0,0,0,0}, ac3 = {0,0,0,0};
  for (int k0 = 0; k0 < K; k0 += 32){
    short8 av = *(const short8*)(ap + k0);
    short8 b0 = *(const short8*)(wp + k0);
    short8 b1 = *(const short8*)(wp + (size_t)16*K + k0);
    short8 b2 = *(const short8*)(wp + (size_t)32*K + k0);
    short8 b3 = *(const short8*)(wp + (size_t)48*K + k0);
    ac0 = __builtin_amdgcn_mfma_f32_16x16x32_bf16(av, b0, ac0, 0, 0, 0);
    ac1 = __builtin_amdgcn_mfma_f32_16x16x32_bf16(av, b1, ac1, 0, 0, 0);
    ac2 = __builtin_amdgcn_mfma_f32_16x16x32_bf16(av, b2, ac2, 0, 0, 0);
    ac3 = __builtin_amdgcn_mfma_f32_16x16x32_bf16(av, b3, ac3, 0, 0, 0);
  }
  const f32x4 accs[4] = {ac0, ac1, ac2, ac3};
  #pragma unroll
  for (int j = 0; j < 4; ++j){
    const int nn = ng*64 + j*16 + r;
    float bias = 0.f;
    if (pb1) bias += pb1[nn];
    if (pb2) bias += pb2[nn];
    bias *= bscale;
    #pragma unroll
    for (int i = 0; i < 4; ++i){
      const int mm = mt*16 + quad*4 + i;
      C[(size_t)mm*N + nn] = f2b(accs[j][i] + bias);
    }
  }
}

// ================= chunked scan =================
// chains (b,c); 4 batch-chains per WG sharing the G stream. 256 WGs.
// FULL=false: zero-init, write only chunk-end state to Z.
// FULL=true : init from S, write every step to nh (bf16).
template<bool FULL>
__global__ __launch_bounds__(512) void scan_pass(
    const ushort* __restrict__ U, const ushort* __restrict__ G8,
    const float* __restrict__ S, float* __restrict__ Z,
    ushort* __restrict__ nh)
{
  const int blk = blockIdx.x;           // 256
  const int c  = blk & (kNC - 1);
  const int b0 = (blk >> 4) * 4;
  const int n  = threadIdx.x;

  __shared__ __align__(16) float hs[4][kH];
  #pragma unroll
  for (int i = 0; i < 4; ++i)
    hs[i][n] = FULL ? S[((size_t)(b0 + i)*kNC + c)*kH + n] : 0.f;
  __syncthreads();

  const ushort* g = G8 + n*8;
  for (int j = 0; j < kC; ++j){
    const int t = c*kC + j;
    float u[4], a[4];
    #pragma unroll
    for (int i = 0; i < 4; ++i){
      u[i] = b2f(U[((size_t)(b0 + i)*kS + t)*kH + n]);
      a[i] = 0.f;
    }
    #pragma unroll 2
    for (int m8 = 0; m8 < kH/8; ++m8){
      const uint4 p = *(const uint4*)(g + (size_t)m8*4096);
      float gv[8];
      unpack2(p.x, gv[0], gv[1]); unpack2(p.y, gv[2], gv[3]);
      unpack2(p.z, gv[4], gv[5]); unpack2(p.w, gv[6], gv[7]);
      #pragma unroll
      for (int i = 0; i < 4; ++i){
        const float4 h0 = *(const float4*)&hs[i][m8*8];
        const float4 h1 = *(const float4*)&hs[i][m8*8 + 4];
        a[i] += gv[0]*h0.x + gv[1]*h0.y + gv[2]*h0.z + gv[3]*h0.w
              + gv[4]*h1.x + gv[5]*h1.y + gv[6]*h1.z + gv[7]*h1.w;
      }
    }
    float nv[4];
    #pragma unroll
    for (int i = 0; i < 4; ++i) nv[i] = 0.9f*hs[i][n] + u[i] + a[i];
    __syncthreads();
    #pragma unroll
    for (int i = 0; i < 4; ++i){
      hs[i][n] = nv[i];
      if (FULL) nh[((size_t)(b0 + i)*kS + t)*kH + n] = f2b(nv[i]);
    }
    __syncthreads();
  }
  if (!FULL){
    #pragma unroll
    for (int i = 0; i < 4; ++i)
      Z[((size_t)(b0 + i)*kNC + c)*kH + n] = hs[i][n];
  }
}

// boundary recursion: S[b][c] = state entering chunk c; s' = s@A32 + Z[b][c]
__global__ __launch_bounds__(512) void scan_boundary(
    const float* __restrict__ A32, const float* __restrict__ Z,
    float* __restrict__ S)
{
  const int b = blockIdx.x, n = threadIdx.x;
  __shared__ float s[kH];
  s[n] = 0.f;
  __syncthreads();
  for (int c = 0; c < kNC; ++c){
    S[((size_t)b*kNC + c)*kH + n] = s[n];
    float acc = 0.f;
    for (int m = 0; m < kH; ++m) acc += s[m] * A32[(size_t)m*kH + n];
    const float nv = acc + Z[((size_t)b*kNC + c)*kH + n];
    __syncthreads();
    s[n] = nv;
    __syncthreads();
  }
}

// ---------------- LayerNorm rows (in place on bf16) ----------------
__global__ __launch_bounds__(512) void ln_rows(
    ushort* __restrict__ act, const float* __restrict__ g, const float* __restrict__ bta)
{
  const size_t row = blockIdx.x;
  const int n = threadIdx.x, wid = n >> 6, lane = n & 63;
  __shared__ float red[16];
  const float y = b2f(act[row*kH + n]);
  float s1 = y, s2 = y*y;
  #pragma unroll
  for (int off = 32; off; off >>= 1){
    s1 += __shfl_down(s1, off); s2 += __shfl_down(s2, off);
  }
  if (lane == 0){ red[wid] = s1; red[8 + wid] = s2; }
  __syncthreads();
  float m = 0.f, q = 0.f;
  #pragma unroll
  for (int i = 0; i < 8; ++i){ m += red[i]; q += red[8+i]; }
  m *= (1.f/kH); q *= (1.f/kH);
  const float var = q - m*m;
  const float hv = (y - m) * rsqrtf(var + EPS) * g[n] + bta[n];
  act[row*kH + n] = f2b(hv);
}

// ---------------- seqmean (fp32) from bf16 act ----------------
__global__ __launch_bounds__(512) void seqmean_k(
    const ushort* __restrict__ act, float* __restrict__ seqmean)
{
  const int b = blockIdx.x, n = threadIdx.x;
  float acc = 0.f;
  for (int t = 0; t < kS; ++t) acc += b2f(act[((size_t)b*kS + t)*kH + n]);
  seqmean[(size_t)b*kH + n] = acc * (1.f/kS);
}

// ---------------- flash attention on precomputed qkv (bf16) ----------------
__global__ __launch_bounds__(512) void attn_chunk(
    const ushort* __restrict__ qkv,   // (16*S, 3H) bf16
    float* __restrict__ aomean, int b0)
{
  const int bb = blockIdx.x >> 3, h = blockIdx.x & 7;
  const int tid = threadIdx.x, lane = tid & 63;
  __shared__ ushort kt[128][72];
  __shared__ ushort vt[128][72];
  __shared__ float aom[kDH];
  if (tid < kDH) aom[tid] = 0.f;

  float q[kDH], o[kDH];
  {
    const uint4* qp = (const uint4*)(qkv + ((size_t)bb*kS + tid)*(3*kH) + h*kDH);
    #pragma unroll
    for (int i = 0; i < 8; ++i){
      uint4 u = qp[i]; float f0,f1,f2,f3,f4,f5,f6,f7;
      unpack2(u.x,f0,f1); unpack2(u.y,f2,f3); unpack2(u.z,f4,f5); unpack2(u.w,f6,f7);
      q[i*8+0]=f0*0.125f; q[i*8+1]=f1*0.125f; q[i*8+2]=f2*0.125f; q[i*8+3]=f3*0.125f;
      q[i*8+4]=f4*0.125f; q[i*8+5]=f5*0.125f; q[i*8+6]=f6*0.125f; q[i*8+7]=f7*0.125f;
    }
  }
  #pragma unroll
  for (int d = 0; d < kDH; ++d) o[d] = 0.f;
  float mmax = -1e30f, lsum = 0.f;

  const int p  = tid & 127;
  const int dg = (tid >> 7) * 16;

  for (int t0 = 0; t0 < kS; t0 += 128){
    __syncthreads();
    const ushort* krow = qkv + ((size_t)bb*kS + t0 + p)*(3*kH) + kH   + h*kDH + dg;
    const ushort* vrow = qkv + ((size_t)bb*kS + t0 + p)*(3*kH) + 2*kH + h*kDH + dg;
    *(uint4*)&kt[p][dg]     = *(const uint4*)krow;
    *(uint4*)&kt[p][dg + 8] = *(const uint4*)(krow + 8);
    *(uint4*)&vt[p][dg]     = *(const uint4*)vrow;
    *(uint4*)&vt[p][dg + 8] = *(const uint4*)(vrow + 8);
    __syncthreads();

    for (int j = 0; j < 128; ++j){
      float s = 0.f;
      const uint4* kp = (const uint4*)&kt[j][0];
      #pragma unroll
      for (int i = 0; i < 8; ++i){
        uint4 u = kp[i]; float f0,f1,f2,f3,f4,f5,f6,f7;
        unpack2(u.x,f0,f1); unpack2(u.y,f2,f3); unpack2(u.z,f4,f5); unpack2(u.w,f6,f7);
        s += q[i*8+0]*f0 + q[i*8+1]*f1 + q[i*8+2]*f2 + q[i*8+3]*f3
           + q[i*8+4]*f4 + q[i*8+5]*f5 + q[i*8+6]*f6 + q[i*8+7]*f7;
      }
      if (s > mmax){
        const float corr = __expf(mmax - s);
        lsum *= corr;
        #pragma unroll
        for (int d = 0; d < kDH; ++d) o[d] *= corr;
        mmax = s;
      }
      const float pw = __expf(s - mmax);
      lsum += pw;
      const uint4* vp = (const uint4*)&vt[j][0];
      #pragma unroll
      for (int i = 0; i < 8; ++i){
        uint4 u = vp[i]; float f0,f1,f2,f3,f4,f5,f6,f7;
        unpack2(u.x,f0,f1); unpack2(u.y,f2,f3); unpack2(u.z,f4,f5); unpack2(u.w,f6,f7);
        o[i*8+0] += pw*f0; o[i*8+1] += pw*f1; o[i*8+2] += pw*f2; o[i*8+3] += pw*f3;
        o[i*8+4] += pw*f4; o[i*8+5] += pw*f5; o[i*8+6] += pw*f6; o[i*8+7] += pw*f7;
      }
    }
  }
  const float invl = 1.f / lsum;
  #pragma unroll
  for (int d = 0; d < kDH; ++d){
    float v = o[d] * invl;
    #pragma unroll
    for (int off = 32; off; off >>= 1) v += __shfl_down(v, off);
    if (lane == 0) atomicAdd(&aom[d], v);
  }
  __syncthreads();
  if (tid < kDH)
    aomean[(size_t)(b0 + bb)*kH + h*kDH + tid] = aom[tid] * (1.f/kS);
}

// ---- pooled = seqmean + aomean@out_w^T + out_b (fp32) ----
__global__ __launch_bounds__(512) void pooled_kernel(
    const float* __restrict__ seqmean, const float* __restrict__ aomean,
    const float* __restrict__ outw, const float* __restrict__ outb,
    float* __restrict__ pooled)
{
  const int b = blockIdx.x, n = threadIdx.x;
  __shared__ float a[kH];
  a[n] = aomean[(size_t)b*kH + n];
  __syncthreads();
  const float* w = outw + (size_t)n*kH;
  float acc = outb[n];
  for (int m = 0; m < kH; ++m) acc += w[m] * a[m];
  pooled[(size_t)b*kH + n] = seqmean[(size_t)b*kH + n] + acc;
}

// ---------------- heads (fp32, validated) ----------------
__global__ __launch_bounds__(256) void heads_kernel(
    const float* __restrict__ pooled,
    const float* Wd1, const float* bd1, const float* Wd2, const float* bd2,
    const float* Wd3, const float* bd3,
    const float* Wq1, const float* bq1, const float* Wq2, const float* bq2,
    const float* Wq3, const float* bq3,
    const float* Wc1, const float* bc1, const float* Wc2, const float* bc2,
    float* __restrict__ out)
{
  const int b = blockIdx.x, tid = threadIdx.x;
  __shared__ float p[kH];
  __shared__ float a1d[256], a1q[256], a1c[256];
  __shared__ float a2d[128], a2q[128];
  p[tid]       = pooled[(size_t)b*kH + tid];
  p[tid + 256] = pooled[(size_t)b*kH + tid + 256];
  __syncthreads();
  {
    const float *w1 = Wd1 + (size_t)tid*kH, *w2 = Wq1 + (size_t)tid*kH,
                *w3 = Wc1 + (size_t)tid*kH;
    float v1 = bd1[tid], v2 = bq1[tid], v3 = bc1[tid];
    for (int m = 0; m < kH; ++m){
      v1 += w1[m]*p[m]; v2 += w2[m]*p[m]; v3 += w3[m]*p[m];
    }
    a1d[tid] = fmaxf(v1, 0.f); a1q[tid] = fmaxf(v2, 0.f); a1c[tid] = fmaxf(v3, 0.f);
  }
  __syncthreads();
  if (tid < 128){
    const float *w1 = Wd2 + (size_t)tid*256, *w2 = Wq2 + (size_t)tid*256;
    float v1 = bd2[tid], v2 = bq2[tid];
    for (int m = 0; m < 256; ++m){ v1 += w1[m]*a1d[m]; v2 += w2[m]*a1q[m]; }
    a2d[tid] = fmaxf(v1, 0.f); a2q[tid] = fmaxf(v2, 0.f);
  }
  __syncthreads();
  if (tid == 0){
    float d0 = bd3[0], d1 = bd3[1], pr = bq3[0], c = bc2[0];
    for (int m = 0; m < 128; ++m){
      d0 += Wd3[m]*a2d[m]; d1 += Wd3[128+m]*a2d[m]; pr += Wq3[m]*a2q[m];
    }
    for (int m = 0; m < 256; ++m) c += Wc2[m]*a1c[m];
    c = 1.f / (1.f + __expf(-c));
    out[2*b + 0]  = d0;
    out[2*b + 1]  = d1;
    out[2*kB + b] = pr;
    out[3*kB + b] = c;
  }
}

// ---------------- launch ----------------
extern "C" void kernel_launch(void* const* d_in, const int* in_sizes, int n_in,
                              void* d_out, int out_size, void* d_ws, size_t ws_size,
                              hipStream_t stream) {
  const float* x    = (const float*)d_in[0];
  const float* Win0 = (const float*)d_in[1];
  const float* bin0 = (const float*)d_in[2];
  const float* Wi   = (const float*)d_in[3];
  const float* bi   = (const float*)d_in[4];
  const float* Wh   = (const float*)d_in[5];
  const float* bh   = (const float*)d_in[6];
  const float* Wo   = (const float*)d_in[7];
  const float* bo   = (const float*)d_in[8];
  const float* lng  = (const float*)d_in[9];
  const float* lnb  = (const float*)d_in[10];
  const float* ipw  = (const float*)d_in[11];
  const float* ipb  = (const float*)d_in[12];
  const float* outw = (const float*)d_in[13];
  const float* outb = (const float*)d_in[14];

  char* wsb = (char*)d_ws;
  const size_t MB = 1u << 20;
  ushort* act   = (ushort*)(wsb);               // 32 MiB
  ushort* U     = (ushort*)(wsb + 32*MB);       // 32 MiB (reused as qkv)
  ushort* nh    = (ushort*)(wsb + 64*MB);       // 32 MiB
  ushort* G8    = (ushort*)(wsb + 96*MB);       // 2 MiB
  ushort* wi_bf = (ushort*)(wsb + 98*MB);       // 2 MiB (0.1-scaled)
  ushort* wo_bf = (ushort*)(wsb + 100*MB);      // 2 MiB
  float*  Afp   = (float*)(wsb + 102*MB);       // 4 MiB (fp32 A powers, ping)
  float*  Afp2  = (float*)(wsb + 106*MB);       // 4 MiB (pong; holds A^32)
  float*  Z     = (float*)(wsb + 110*MB);       // 2 MiB (chunk-end zero-init states)
  float*  S     = (float*)(wsb + 112*MB);       // 2 MiB (chunk-entry true states)
  ushort* w0_bf = (ushort*)(wsb + 114*MB);      // 64 KiB
  ushort* ip_bf = (ushort*)(wsb + 114*MB + 65536);            // 1.5 MiB
  ushort* x_bf  = (ushort*)(wsb + 114*MB + 65536 + 1572864);  // 4 MiB
  char*   tail  = wsb + 114*MB + 65536 + 1572864 + 4194304;
  float* seqmean = (float*)tail;
  float* aomean  = seqmean + (size_t)kB*kH;
  float* pooled  = aomean  + (size_t)kB*kH;
  ushort* qkv    = U;   // overlay: U dead after scan phase

  // ---- prep casts ----
  cast_scale<<<(kB*kS*kF + 255)/256, 256, 0, stream>>>(x, x_bf, kB*kS*kF, 1.f);
  cast_scale<<<(kH*kF + 255)/256, 256, 0, stream>>>(Win0, w0_bf, kH*kF, 1.f);
  cast_scale<<<(kL*kH*kH + 255)/256, 256, 0, stream>>>(Wi, wi_bf, kL*kH*kH, 0.1f);
  cast_scale<<<(kL*kH*kH + 255)/256, 256, 0, stream>>>(Wo, wo_bf, kL*kH*kH, 1.f);
  cast_scale<<<(3*kH*kH + 255)/256, 256, 0, stream>>>(ipw, ip_bf, 3*kH*kH, 1.f);
  prep_g8<<<(kL*kH*kH + 255)/256, 256, 0, stream>>>(Wh, G8);
  prep_afp<<<(kL*kH*kH + 255)/256, 256, 0, stream>>>(Wh, Afp);
  // A^32 for all 4 layers via 5 fp32 squarings (ends in Afp2)
  sqgemm<<<kL*64, 512, 0, stream>>>(Afp,  Afp2);   // A^2
  sqgemm<<<kL*64, 512, 0, stream>>>(Afp2, Afp);    // A^4
  sqgemm<<<kL*64, 512, 0, stream>>>(Afp,  Afp2);   // A^8
  sqgemm<<<kL*64, 512, 0, stream>>>(Afp2, Afp);    // A^16
  sqgemm<<<kL*64, 512, 0, stream>>>(Afp,  Afp2);   // A^32

  constexpr int M = kB*kS;   // 32768
  gemm_bf16<<<(M/16)*(kH/64)/4, 256, 0, stream>>>(x_bf, w0_bf, act, M, kH, kF,
                                                  bin0, nullptr, 1.f);
  for (int l = 0; l < kL; ++l){
    gemm_bf16<<<(M/16)*(kH/64)/4, 256, 0, stream>>>(
        act, wi_bf + (size_t)l*kH*kH, U, M, kH, kH,
        bi + (size_t)l*kH, bh + (size_t)l*kH, 0.1f);
    scan_pass<false><<<256, kH, 0, stream>>>(U, G8 + (size_t)l*kH*kH,
                                             nullptr, Z, nullptr);
    scan_boundary<<<kB, kH, 0, stream>>>(Afp2 + (size_t)l*kH*kH, Z, S);
    scan_pass<true><<<256, kH, 0, stream>>>(U, G8 + (size_t)l*kH*kH,
                                            S, nullptr, nh);
    gemm_bf16<<<(M/16)*(kH/64)/4, 256, 0, stream>>>(
        nh, wo_bf + (size_t)l*kH*kH, act, M, kH, kH,
        bo + (size_t)l*kH, nullptr, 1.f);
    ln_rows<<<M, kH, 0, stream>>>(act, lng + (size_t)l*kH, lnb + (size_t)l*kH);
  }

  seqmean_k<<<kB, kH, 0, stream>>>(act, seqmean);

  for (int c = 0; c < 4; ++c){
    const int Mc = 16*kS;   // 8192
    gemm_bf16<<<(Mc/16)*(3*kH/64)/4, 256, 0, stream>>>(
        act + (size_t)c*Mc*kH, ip_bf, qkv, Mc, 3*kH, kH, ipb, nullptr, 1.f);
    attn_chunk<<<16*8, kH, 0, stream>>>(qkv, aomean, c*16);
  }

  pooled_kernel<<<kB, kH, 0, stream>>>(seqmean, aomean, outw, outb, pooled);

  heads_kernel<<<kB, 256, 0, stream>>>(pooled,
      (const float*)d_in[15], (const float*)d_in[16], (const float*)d_in[17],
      (const float*)d_in[18], (const float*)d_in[19], (const float*)d_in[20],
      (const float*)d_in[21], (const float*)d_in[22], (const float*)d_in[23],
      (const float*)d_in[24], (const float*)d_in[25], (const float*)d_in[26],
      (const float*)d_in[27], (const float*)d_in[28], (const float*)d_in[29],
      (const float*)d_in[30], (float*)d_out);
}